// Round 12
// baseline (609.435 us; speedup 1.0000x reference)
//
#include <hip/hip_runtime.h>
#include <hip/hip_bf16.h>
#include <math.h>

#define NN 100000      // nodes
#define NE 1000000     // real edges (self-loops handled analytically)
#define HD 64          // hidden / feature dim
#define NG 128         // graphs
#define NEG_SLOPE 0.2f
#define NBLK 391       // ceil(NN/256)

__device__ __forceinline__ float bf2f(unsigned short u) {
    return __uint_as_float(((unsigned)u) << 16);
}
__device__ __forceinline__ unsigned short f2bf(float f) {
    __hip_bfloat16 h = __float2bfloat16(f);
    return *reinterpret_cast<unsigned short*>(&h);
}
__device__ __forceinline__ float lrelu_exp(float e) {
    e = e > 0.f ? e : NEG_SLOPE * e;
    return __expf(e);
}
#define RFL __builtin_amdgcn_readfirstlane

// ---------------- CSR build (real edges only; deg memset to 0 outside) ----

__global__ __launch_bounds__(256) void k_hist(const int* __restrict__ edst,
                                              int* __restrict__ deg) {
    int e = blockIdx.x * 256 + threadIdx.x;
    if (e < NE) atomicAdd(&deg[edst[e]], 1);
}

__global__ __launch_bounds__(256) void k_bsum(const int* __restrict__ deg,
                                              int* __restrict__ bsum) {
    __shared__ int sm[256];
    int i = blockIdx.x * 256 + threadIdx.x;
    sm[threadIdx.x] = (i < NN) ? deg[i] : 0;
    __syncthreads();
    #pragma unroll
    for (int s = 128; s > 0; s >>= 1) {
        if (threadIdx.x < s) sm[threadIdx.x] += sm[threadIdx.x + s];
        __syncthreads();
    }
    if (threadIdx.x == 0) bsum[blockIdx.x] = sm[0];
}

__global__ __launch_bounds__(512) void k_scanb(const int* __restrict__ bsum,
                                               int* __restrict__ boff) {
    __shared__ int sm[512];
    int t = threadIdx.x;
    int v = (t < NBLK) ? bsum[t] : 0;
    sm[t] = v;
    __syncthreads();
    #pragma unroll
    for (int s = 1; s < 512; s <<= 1) {
        int add = (t >= s) ? sm[t - s] : 0;
        __syncthreads();
        sm[t] += add;
        __syncthreads();
    }
    if (t < NBLK) boff[t] = sm[t] - v;   // exclusive
}

__global__ __launch_bounds__(256) void k_scan2(const int* __restrict__ deg,
                                               const int* __restrict__ boff,
                                               int* __restrict__ row,
                                               int* __restrict__ cursor) {
    __shared__ int sm[256];
    int t = threadIdx.x, i = blockIdx.x * 256 + t;
    int v = (i < NN) ? deg[i] : 0;
    sm[t] = v;
    __syncthreads();
    #pragma unroll
    for (int s = 1; s < 256; s <<= 1) {
        int add = (t >= s) ? sm[t - s] : 0;
        __syncthreads();
        sm[t] += add;
        __syncthreads();
    }
    int excl = boff[blockIdx.x] + sm[t] - v;
    if (i < NN) { row[i] = excl; cursor[i] = excl; }
    if (i == NN - 1) row[NN] = excl + v;
}

// XCD-partitioned scatter (proven R8): writes for a 512-node dst group stay
// in one XCD's L2.
__global__ __launch_bounds__(256) void k_scatter(const int* __restrict__ esrc,
                                                 const int* __restrict__ edst,
                                                 int* __restrict__ cursor,
                                                 int* __restrict__ ssrc) {
    int xcd = blockIdx.x & 7;
    int chunk = blockIdx.x >> 3;
    int base = chunk * 4096;
    #pragma unroll 1
    for (int r = 0; r < 16; ++r) {
        int e = base + (r << 8) + threadIdx.x;
        if (e < NE) {
            int d = edst[e];
            if (((d >> 9) & 7) == xcd) {
                int pos = atomicAdd(&cursor[d], 1);
                ssrc[pos] = esrc[e];
            }
        }
    }
}

// ---------------- layer-0 transform (from fp32 x) ----------------
__global__ __launch_bounds__(256) void k_transform0(
    const float* __restrict__ inp, const float* __restrict__ W,
    const float* __restrict__ a_src, const float* __restrict__ a_dst,
    unsigned short* __restrict__ hb,
    float* __restrict__ alpha_s, float* __restrict__ alpha_d)
{
    __shared__ float sx[256];
    int node = (blockIdx.x * 256 + threadIdx.x) >> 6;
    int lane = threadIdx.x & 63;
    sx[threadIdx.x] = inp[(size_t)node * HD + lane];
    __syncthreads();
    const float* sxw = sx + (threadIdx.x & 192);
    float hj = 0.f;
    #pragma unroll
    for (int k4 = 0; k4 < 16; ++k4) {
        float4 xv = reinterpret_cast<const float4*>(sxw)[k4];
        int kb = k4 * 4;
        hj = fmaf(xv.x, W[(kb + 0) * HD + lane], hj);
        hj = fmaf(xv.y, W[(kb + 1) * HD + lane], hj);
        hj = fmaf(xv.z, W[(kb + 2) * HD + lane], hj);
        hj = fmaf(xv.w, W[(kb + 3) * HD + lane], hj);
    }
    hb[(size_t)node * HD + lane] = f2bf(hj);
    float s = hj * a_src[lane];
    float d = hj * a_dst[lane];
    #pragma unroll
    for (int off = 32; off > 0; off >>= 1) {
        s += __shfl_xor(s, off, 64);
        d += __shfl_xor(d, off, 64);
    }
    if (lane == 0) { alpha_s[node] = s; alpha_d[node] = d; }
}

// ------------- aggregate: DUAL-NODE interleave, wave-uniform --------------
// Each wave owns two nodes (nA, nB = nA+1 within its pair-slot). Main loop
// advances 4 edges of each per iteration: 8 independent gathers in flight,
// two chains, all indices scalar (readfirstlane), branches wave-uniform.

__device__ __forceinline__ void edge4(
    int i, float ad, int lane,
    const int* __restrict__ ssrc, const float* __restrict__ as_in,
    const unsigned short* __restrict__ hb_in, float& acc, float& den)
{
    int s0 = RFL(ssrc[i]);
    int s1 = RFL(ssrc[i + 1]);
    int s2 = RFL(ssrc[i + 2]);
    int s3 = RFL(ssrc[i + 3]);
    float a0 = as_in[s0], a1 = as_in[s1], a2 = as_in[s2], a3 = as_in[s3];
    unsigned short u0 = hb_in[(size_t)s0 * HD + lane];
    unsigned short u1 = hb_in[(size_t)s1 * HD + lane];
    unsigned short u2 = hb_in[(size_t)s2 * HD + lane];
    unsigned short u3 = hb_in[(size_t)s3 * HD + lane];
    float w0 = lrelu_exp(a0 + ad), w1 = lrelu_exp(a1 + ad);
    float w2 = lrelu_exp(a2 + ad), w3 = lrelu_exp(a3 + ad);
    acc = fmaf(w0, bf2f(u0), acc);
    acc = fmaf(w1, bf2f(u1), acc);
    acc = fmaf(w2, bf2f(u2), acc);
    acc = fmaf(w3, bf2f(u3), acc);
    den += (w0 + w1) + (w2 + w3);
}

__device__ __forceinline__ void drain(
    int i, int end, float ad, int lane,
    const int* __restrict__ ssrc, const float* __restrict__ as_in,
    const unsigned short* __restrict__ hb_in, float& acc, float& den)
{
    for (; i + 4 <= end; i += 4)
        edge4(i, ad, lane, ssrc, as_in, hb_in, acc, den);
    for (; i < end; ++i) {
        int s0 = RFL(ssrc[i]);
        float w0 = lrelu_exp(as_in[s0] + ad);
        acc = fmaf(w0, bf2f(hb_in[(size_t)s0 * HD + lane]), acc);
        den += w0;
    }
}

__device__ __forceinline__ void aggr2(
    int nA, int nB, int lane,
    const int* __restrict__ row, const int* __restrict__ ssrc,
    const float* __restrict__ as_in, const float* __restrict__ ad_in,
    const unsigned short* __restrict__ hb_in,
    float& accAo, float& denAo, float& accBo, float& denBo)
{
    int begA = row[nA], endA = row[nA + 1];
    int begB = row[nB], endB = row[nB + 1];
    float adA = ad_in[nA], adB = ad_in[nB];
    // self loops
    float wA = lrelu_exp(as_in[nA] + adA);
    float wB = lrelu_exp(as_in[nB] + adB);
    float accA = wA * bf2f(hb_in[(size_t)nA * HD + lane]);
    float accB = wB * bf2f(hb_in[(size_t)nB * HD + lane]);
    float denA = wA, denB = wB;
    int iA = begA, iB = begB;
    // interleaved main loop: 4 edges of A + 4 edges of B per iteration
    while (iA + 4 <= endA && iB + 4 <= endB) {
        int a0 = RFL(ssrc[iA]);
        int a1 = RFL(ssrc[iA + 1]);
        int a2 = RFL(ssrc[iA + 2]);
        int a3 = RFL(ssrc[iA + 3]);
        int b0 = RFL(ssrc[iB]);
        int b1 = RFL(ssrc[iB + 1]);
        int b2 = RFL(ssrc[iB + 2]);
        int b3 = RFL(ssrc[iB + 3]);
        float aa0 = as_in[a0], aa1 = as_in[a1], aa2 = as_in[a2], aa3 = as_in[a3];
        float ab0 = as_in[b0], ab1 = as_in[b1], ab2 = as_in[b2], ab3 = as_in[b3];
        unsigned short uA0 = hb_in[(size_t)a0 * HD + lane];
        unsigned short uA1 = hb_in[(size_t)a1 * HD + lane];
        unsigned short uA2 = hb_in[(size_t)a2 * HD + lane];
        unsigned short uA3 = hb_in[(size_t)a3 * HD + lane];
        unsigned short uB0 = hb_in[(size_t)b0 * HD + lane];
        unsigned short uB1 = hb_in[(size_t)b1 * HD + lane];
        unsigned short uB2 = hb_in[(size_t)b2 * HD + lane];
        unsigned short uB3 = hb_in[(size_t)b3 * HD + lane];
        float wA0 = lrelu_exp(aa0 + adA), wA1 = lrelu_exp(aa1 + adA);
        float wA2 = lrelu_exp(aa2 + adA), wA3 = lrelu_exp(aa3 + adA);
        float wB0 = lrelu_exp(ab0 + adB), wB1 = lrelu_exp(ab1 + adB);
        float wB2 = lrelu_exp(ab2 + adB), wB3 = lrelu_exp(ab3 + adB);
        accA = fmaf(wA0, bf2f(uA0), accA);
        accA = fmaf(wA1, bf2f(uA1), accA);
        accA = fmaf(wA2, bf2f(uA2), accA);
        accA = fmaf(wA3, bf2f(uA3), accA);
        accB = fmaf(wB0, bf2f(uB0), accB);
        accB = fmaf(wB1, bf2f(uB1), accB);
        accB = fmaf(wB2, bf2f(uB2), accB);
        accB = fmaf(wB3, bf2f(uB3), accB);
        denA += (wA0 + wA1) + (wA2 + wA3);
        denB += (wB0 + wB1) + (wB2 + wB3);
        iA += 4; iB += 4;
    }
    drain(iA, endA, adA, lane, ssrc, as_in, hb_in, accA, denA);
    drain(iB, endB, adB, lane, ssrc, as_in, hb_in, accB, denB);
    accAo = accA; denAo = denA; accBo = accB; denBo = denB;
}

// aggregate layer l (2 nodes/wave) + fused transform of layer l+1
__global__ __launch_bounds__(256) void k_aggr_ft(
    const int* __restrict__ row, const int* __restrict__ ssrc,
    const float* __restrict__ as_in, const float* __restrict__ ad_in,
    const unsigned short* __restrict__ hb_in,
    const float* __restrict__ bprev, const float* __restrict__ Wn,
    const float* __restrict__ asn, const float* __restrict__ adn,
    unsigned short* __restrict__ hb_out,
    float* __restrict__ as_out, float* __restrict__ ad_out)
{
    __shared__ float sx[256];
    int wslot = RFL(threadIdx.x >> 6);
    int nA = blockIdx.x * 8 + wslot * 2;
    int nB = nA + 1;
    int lane = threadIdx.x & 63;

    float accA, denA, accB, denB;
    aggr2(nA, nB, lane, row, ssrc, as_in, ad_in, hb_in, accA, denA, accB, denB);

    float bp = bprev[lane];
    float asl = asn[lane], adl = adn[lane];
    #pragma unroll
    for (int half = 0; half < 2; ++half) {
        int node = half ? nB : nA;
        float acc = half ? accB : accA;
        float den = half ? denB : denA;
        float xe = fmaf(acc, 1.f / den, bp);
        xe = xe > 0.f ? xe : 0.f;
        sx[threadIdx.x] = xe;   // same-wave write/read: no barrier needed
        const float* sxw = sx + (threadIdx.x & 192);
        float hj = 0.f;
        #pragma unroll
        for (int k4 = 0; k4 < 16; ++k4) {
            float4 xv = reinterpret_cast<const float4*>(sxw)[k4];
            int kb = k4 * 4;
            hj = fmaf(xv.x, Wn[(kb + 0) * HD + lane], hj);
            hj = fmaf(xv.y, Wn[(kb + 1) * HD + lane], hj);
            hj = fmaf(xv.z, Wn[(kb + 2) * HD + lane], hj);
            hj = fmaf(xv.w, Wn[(kb + 3) * HD + lane], hj);
        }
        hb_out[(size_t)node * HD + lane] = f2bf(hj);
        float s = hj * asl;
        float d = hj * adl;
        #pragma unroll
        for (int off = 32; off > 0; off >>= 1) {
            s += __shfl_xor(s, off, 64);
            d += __shfl_xor(d, off, 64);
        }
        if (lane == 0) { as_out[node] = s; ad_out[node] = d; }
    }
}

// aggregate last layer (2 nodes/wave) + fused gate
__global__ __launch_bounds__(256) void k_aggr_gate(
    const int* __restrict__ row, const int* __restrict__ ssrc,
    const float* __restrict__ as_in, const float* __restrict__ ad_in,
    const unsigned short* __restrict__ hb_in,
    const float* __restrict__ b2, const float* __restrict__ gate_w,
    const float* __restrict__ gate_b,
    float* __restrict__ h3out, float* __restrict__ gvals)
{
    int wslot = RFL(threadIdx.x >> 6);
    int nA = blockIdx.x * 8 + wslot * 2;
    int nB = nA + 1;
    int lane = threadIdx.x & 63;

    float accA, denA, accB, denB;
    aggr2(nA, nB, lane, row, ssrc, as_in, ad_in, hb_in, accA, denA, accB, denB);

    float b2l = b2[lane], gwl = gate_w[lane], gb = gate_b[0];
    #pragma unroll
    for (int half = 0; half < 2; ++half) {
        int node = half ? nB : nA;
        float acc = half ? accB : accA;
        float den = half ? denB : denA;
        float h3 = fmaf(acc, 1.f / den, b2l);
        h3out[(size_t)node * HD + lane] = h3;
        float s = h3 * gwl;
        #pragma unroll
        for (int off = 32; off > 0; off >>= 1) s += __shfl_xor(s, off, 64);
        if (lane == 0) gvals[node] = s + gb;
    }
}

__device__ __forceinline__ int lower_bound_batch(const int* __restrict__ batch, int val) {
    int lo = 0, hi = NN;
    while (lo < hi) { int mid = (lo + hi) >> 1; if (batch[mid] < val) lo = mid + 1; else hi = mid; }
    return lo;
}

// One block per graph: softmax-pool + fused final linear
__global__ __launch_bounds__(256) void k_pool(
    const float* __restrict__ h3, const float* __restrict__ gvals,
    const int* __restrict__ batch, const float* __restrict__ lin_w,
    const float* __restrict__ lin_b, float* __restrict__ out)
{
    __shared__ float red[256];
    __shared__ float pooled[HD];
    __shared__ float s_sumexp;
    int g = blockIdx.x;
    int tid = threadIdx.x;
    int start = lower_bound_batch(batch, g);
    int end   = lower_bound_batch(batch, g + 1);

    float local = 0.f;
    for (int n = start + tid; n < end; n += 256) local += __expf(gvals[n]);
    red[tid] = local;
    __syncthreads();
    #pragma unroll
    for (int s = 128; s > 0; s >>= 1) {
        if (tid < s) red[tid] += red[tid + s];
        __syncthreads();
    }
    if (tid == 0) s_sumexp = red[0];
    __syncthreads();
    float inv = 1.f / s_sumexp;

    int wid = tid >> 6, lane = tid & 63;
    float acc = 0.f;
    for (int n = start + wid; n < end; n += 4) {
        float c = __expf(gvals[n]) * inv;
        acc = fmaf(c, h3[(size_t)n * HD + lane], acc);
    }
    __syncthreads();
    red[tid] = acc;
    __syncthreads();
    if (tid < 64) pooled[tid] = red[tid] + red[tid + 64] + red[tid + 128] + red[tid + 192];
    __syncthreads();

    if (tid < 64) {
        float o = lin_b[tid];
        #pragma unroll 8
        for (int c = 0; c < HD; ++c) o = fmaf(pooled[c], lin_w[c * HD + tid], o);
        out[g * HD + tid] = o;
    }
}

extern "C" void kernel_launch(void* const* d_in, const int* in_sizes, int n_in,
                              void* d_out, int out_size, void* d_ws, size_t ws_size,
                              hipStream_t stream)
{
    const float* x     = (const float*)d_in[0];
    const int*  ei     = (const int*)d_in[1];
    const int*  batch  = (const int*)d_in[2];
    const float* W[3]  = {(const float*)d_in[3], (const float*)d_in[7],  (const float*)d_in[11]};
    const float* as[3] = {(const float*)d_in[4], (const float*)d_in[8],  (const float*)d_in[12]};
    const float* ad[3] = {(const float*)d_in[5], (const float*)d_in[9],  (const float*)d_in[13]};
    const float* bb[3] = {(const float*)d_in[6], (const float*)d_in[10], (const float*)d_in[14]};
    const float* gate_w = (const float*)d_in[15];
    const float* gate_b = (const float*)d_in[16];
    const float* lin_w  = (const float*)d_in[17];
    const float* lin_b  = (const float*)d_in[18];
    float* out = (float*)d_out;

    const int* esrc = ei;
    const int* edst = ei + NE;

    float* wsf = (float*)d_ws;
    size_t off = 0;
    float* h3buf = wsf + off; off += (size_t)NN * HD;
    float* asA   = wsf + off; off += NN;
    float* adA   = wsf + off; off += NN;
    float* asB   = wsf + off; off += NN;
    float* adB   = wsf + off; off += NN;
    float* gvals = wsf + off; off += NN;
    unsigned short* hbA = (unsigned short*)(wsf + off); off += (size_t)NN * HD / 2;
    unsigned short* hbB = (unsigned short*)(wsf + off); off += (size_t)NN * HD / 2;
    int* wsi = (int*)(wsf + off);
    size_t ioff = 0;
    int* deg    = wsi + ioff; ioff += NN;
    int* row    = wsi + ioff; ioff += NN + 1;
    int* cursor = wsi + ioff; ioff += NN;
    int* bsum   = wsi + ioff; ioff += NBLK;
    int* boff   = wsi + ioff; ioff += NBLK;
    int* ssrc   = wsi + ioff; ioff += NE;

    dim3 blk(256);
    const int nodeBlocks64 = NN / 4;     // wave per node (transform0)
    const int nodeBlocks2  = NN / 8;     // 2 nodes per wave (aggr)
    const int edgeBlocks   = (NE + 255) / 256;

    // ---- CSR build (real edges only) ----
    (void)hipMemsetAsync(deg, 0, NN * sizeof(int), stream);
    k_hist<<<edgeBlocks, blk, 0, stream>>>(edst, deg);
    k_bsum<<<NBLK, blk, 0, stream>>>(deg, bsum);
    k_scanb<<<1, 512, 0, stream>>>(bsum, boff);
    k_scan2<<<NBLK, blk, 0, stream>>>(deg, boff, row, cursor);
    k_scatter<<<2048, blk, 0, stream>>>(esrc, edst, cursor, ssrc);

    // ---- layer 0 transform ----
    k_transform0<<<nodeBlocks64, blk, 0, stream>>>(x, W[0], as[0], ad[0],
                                                   hbA, asA, adA);
    // ---- layer 0 aggr + layer 1 transform ----
    k_aggr_ft<<<nodeBlocks2, blk, 0, stream>>>(row, ssrc, asA, adA, hbA,
                                               bb[0], W[1], as[1], ad[1],
                                               hbB, asB, adB);
    // ---- layer 1 aggr + layer 2 transform ----
    k_aggr_ft<<<nodeBlocks2, blk, 0, stream>>>(row, ssrc, asB, adB, hbB,
                                               bb[1], W[2], as[2], ad[2],
                                               hbA, asA, adA);
    // ---- layer 2 aggr + gate ----
    k_aggr_gate<<<nodeBlocks2, blk, 0, stream>>>(row, ssrc, asA, adA, hbA,
                                                 bb[2], gate_w, gate_b,
                                                 h3buf, gvals);
    // ---- pooling + final linear ----
    k_pool<<<NG, blk, 0, stream>>>(h3buf, gvals, batch, lin_w, lin_b, out);
}

// Round 14
// 398.453 us; speedup vs baseline: 1.5295x; 1.5295x over previous
//
#include <hip/hip_runtime.h>
#include <hip/hip_bf16.h>
#include <math.h>

#define NN 100000      // nodes
#define NE 1000000     // real edges (self-loops handled analytically)
#define HD 64          // hidden / feature dim
#define NG 128         // graphs
#define NEG_SLOPE 0.2f
#define NBLK 391       // ceil(NN/256)

__device__ __forceinline__ float bf2f(unsigned short u) {
    return __uint_as_float(((unsigned)u) << 16);
}
__device__ __forceinline__ unsigned short f2bf(float f) {
    __hip_bfloat16 h = __float2bfloat16(f);
    return *reinterpret_cast<unsigned short*>(&h);
}
#define RFL __builtin_amdgcn_readfirstlane

// ---------------- CSR build (real edges only; deg memset to 0 outside) ----

__global__ __launch_bounds__(256) void k_hist(const int* __restrict__ edst,
                                              int* __restrict__ deg) {
    int e = blockIdx.x * 256 + threadIdx.x;
    if (e < NE) atomicAdd(&deg[edst[e]], 1);
}

__global__ __launch_bounds__(256) void k_bsum(const int* __restrict__ deg,
                                              int* __restrict__ bsum) {
    __shared__ int sm[256];
    int i = blockIdx.x * 256 + threadIdx.x;
    sm[threadIdx.x] = (i < NN) ? deg[i] : 0;
    __syncthreads();
    #pragma unroll
    for (int s = 128; s > 0; s >>= 1) {
        if (threadIdx.x < s) sm[threadIdx.x] += sm[threadIdx.x + s];
        __syncthreads();
    }
    if (threadIdx.x == 0) bsum[blockIdx.x] = sm[0];
}

__global__ __launch_bounds__(512) void k_scanb(const int* __restrict__ bsum,
                                               int* __restrict__ boff) {
    __shared__ int sm[512];
    int t = threadIdx.x;
    int v = (t < NBLK) ? bsum[t] : 0;
    sm[t] = v;
    __syncthreads();
    #pragma unroll
    for (int s = 1; s < 512; s <<= 1) {
        int add = (t >= s) ? sm[t - s] : 0;
        __syncthreads();
        sm[t] += add;
        __syncthreads();
    }
    if (t < NBLK) boff[t] = sm[t] - v;   // exclusive
}

__global__ __launch_bounds__(256) void k_scan2(const int* __restrict__ deg,
                                               const int* __restrict__ boff,
                                               int* __restrict__ row,
                                               int* __restrict__ cursor) {
    __shared__ int sm[256];
    int t = threadIdx.x, i = blockIdx.x * 256 + t;
    int v = (i < NN) ? deg[i] : 0;
    sm[t] = v;
    __syncthreads();
    #pragma unroll
    for (int s = 1; s < 256; s <<= 1) {
        int add = (t >= s) ? sm[t - s] : 0;
        __syncthreads();
        sm[t] += add;
        __syncthreads();
    }
    int excl = boff[blockIdx.x] + sm[t] - v;
    if (i < NN) { row[i] = excl; cursor[i] = excl; }
    if (i == NN - 1) row[NN] = excl + v;
}

// XCD-partitioned scatter (proven R8): writes for a 512-node dst group stay
// in one XCD's L2.
__global__ __launch_bounds__(256) void k_scatter(const int* __restrict__ esrc,
                                                 const int* __restrict__ edst,
                                                 int* __restrict__ cursor,
                                                 int* __restrict__ ssrc) {
    int xcd = blockIdx.x & 7;
    int chunk = blockIdx.x >> 3;
    int base = chunk * 4096;
    #pragma unroll 1
    for (int r = 0; r < 16; ++r) {
        int e = base + (r << 8) + threadIdx.x;
        if (e < NE) {
            int d = edst[e];
            if (((d >> 9) & 7) == xcd) {
                int pos = atomicAdd(&cursor[d], 1);
                ssrc[pos] = esrc[e];
            }
        }
    }
}

// ---------------- layer-0 transform (from fp32 x) ----------------
// h(bf16) = x @ W ; a4 = (exp(as), exp(.2as), exp(ad), exp(.2ad))
__global__ __launch_bounds__(256) void k_transform0(
    const float* __restrict__ inp, const float* __restrict__ W,
    const float* __restrict__ a_src, const float* __restrict__ a_dst,
    unsigned short* __restrict__ hb, float4* __restrict__ a4_out)
{
    __shared__ float sx[256];
    int node = (blockIdx.x * 256 + threadIdx.x) >> 6;
    int lane = threadIdx.x & 63;
    sx[threadIdx.x] = inp[(size_t)node * HD + lane];
    __syncthreads();
    const float* sxw = sx + (threadIdx.x & 192);
    float hj = 0.f;
    #pragma unroll
    for (int k4 = 0; k4 < 16; ++k4) {
        float4 xv = reinterpret_cast<const float4*>(sxw)[k4];
        int kb = k4 * 4;
        hj = fmaf(xv.x, W[(kb + 0) * HD + lane], hj);
        hj = fmaf(xv.y, W[(kb + 1) * HD + lane], hj);
        hj = fmaf(xv.z, W[(kb + 2) * HD + lane], hj);
        hj = fmaf(xv.w, W[(kb + 3) * HD + lane], hj);
    }
    hb[(size_t)node * HD + lane] = f2bf(hj);
    float s = hj * a_src[lane];
    float d = hj * a_dst[lane];
    #pragma unroll
    for (int off = 32; off > 0; off >>= 1) {
        s += __shfl_xor(s, off, 64);
        d += __shfl_xor(d, off, 64);
    }
    if (lane == 0) {
        float4 o;
        o.x = __expf(s); o.y = __expf(NEG_SLOPE * s);
        o.z = __expf(d); o.w = __expf(NEG_SLOPE * d);
        a4_out[node] = o;
    }
}

// ------------- aggregate core: 1 node per wave, lane = channel ------------
// Wave-uniform edge walk (readfirstlane -> scalar loads for edge metadata,
// full-wave 128B gathers for h). 8-deep pipeline. Edge weight without exp:
//   w = exp(lrelu(as+ad)) = max(exp(as)exp(ad), exp(.2as)exp(.2ad))
// (lrelu(e) = max(e, 0.2e) for slope<1; exp monotone) using precomputed
// per-node exponentials -> 5 full-rate VALU per edge, no transcendentals.
__device__ __forceinline__ void aggr_core(
    int node, int lane,
    const int* __restrict__ row, const int* __restrict__ ssrc,
    const float4* __restrict__ a4,
    const unsigned short* __restrict__ hb_in,
    float& accN, float& denN)
{
    const float2* a2 = reinterpret_cast<const float2*>(a4); // a2[2n]=(easp,easn)
    int beg = row[node], end = row[node + 1];
    float4 an = a4[node];
    float eadp = an.z, eadn = an.w;
    // self loop
    float w = fmaxf(an.x * eadp, an.y * eadn);
    float acc = w * bf2f(hb_in[(size_t)node * HD + lane]);
    float den = w;
    int i = beg;
    for (; i + 8 <= end; i += 8) {
        int s0 = RFL(ssrc[i]);
        int s1 = RFL(ssrc[i + 1]);
        int s2 = RFL(ssrc[i + 2]);
        int s3 = RFL(ssrc[i + 3]);
        int s4 = RFL(ssrc[i + 4]);
        int s5 = RFL(ssrc[i + 5]);
        int s6 = RFL(ssrc[i + 6]);
        int s7 = RFL(ssrc[i + 7]);
        float2 e0 = a2[2 * s0], e1 = a2[2 * s1], e2 = a2[2 * s2], e3 = a2[2 * s3];
        float2 e4 = a2[2 * s4], e5 = a2[2 * s5], e6 = a2[2 * s6], e7 = a2[2 * s7];
        unsigned short u0 = hb_in[(size_t)s0 * HD + lane];
        unsigned short u1 = hb_in[(size_t)s1 * HD + lane];
        unsigned short u2 = hb_in[(size_t)s2 * HD + lane];
        unsigned short u3 = hb_in[(size_t)s3 * HD + lane];
        unsigned short u4 = hb_in[(size_t)s4 * HD + lane];
        unsigned short u5 = hb_in[(size_t)s5 * HD + lane];
        unsigned short u6 = hb_in[(size_t)s6 * HD + lane];
        unsigned short u7 = hb_in[(size_t)s7 * HD + lane];
        float w0 = fmaxf(e0.x * eadp, e0.y * eadn);
        float w1 = fmaxf(e1.x * eadp, e1.y * eadn);
        float w2 = fmaxf(e2.x * eadp, e2.y * eadn);
        float w3 = fmaxf(e3.x * eadp, e3.y * eadn);
        float w4 = fmaxf(e4.x * eadp, e4.y * eadn);
        float w5 = fmaxf(e5.x * eadp, e5.y * eadn);
        float w6 = fmaxf(e6.x * eadp, e6.y * eadn);
        float w7 = fmaxf(e7.x * eadp, e7.y * eadn);
        acc = fmaf(w0, bf2f(u0), acc);
        acc = fmaf(w1, bf2f(u1), acc);
        acc = fmaf(w2, bf2f(u2), acc);
        acc = fmaf(w3, bf2f(u3), acc);
        acc = fmaf(w4, bf2f(u4), acc);
        acc = fmaf(w5, bf2f(u5), acc);
        acc = fmaf(w6, bf2f(u6), acc);
        acc = fmaf(w7, bf2f(u7), acc);
        den += ((w0 + w1) + (w2 + w3)) + ((w4 + w5) + (w6 + w7));
    }
    for (; i + 4 <= end; i += 4) {
        int s0 = RFL(ssrc[i]);
        int s1 = RFL(ssrc[i + 1]);
        int s2 = RFL(ssrc[i + 2]);
        int s3 = RFL(ssrc[i + 3]);
        float2 e0 = a2[2 * s0], e1 = a2[2 * s1], e2 = a2[2 * s2], e3 = a2[2 * s3];
        unsigned short u0 = hb_in[(size_t)s0 * HD + lane];
        unsigned short u1 = hb_in[(size_t)s1 * HD + lane];
        unsigned short u2 = hb_in[(size_t)s2 * HD + lane];
        unsigned short u3 = hb_in[(size_t)s3 * HD + lane];
        float w0 = fmaxf(e0.x * eadp, e0.y * eadn);
        float w1 = fmaxf(e1.x * eadp, e1.y * eadn);
        float w2 = fmaxf(e2.x * eadp, e2.y * eadn);
        float w3 = fmaxf(e3.x * eadp, e3.y * eadn);
        acc = fmaf(w0, bf2f(u0), acc);
        acc = fmaf(w1, bf2f(u1), acc);
        acc = fmaf(w2, bf2f(u2), acc);
        acc = fmaf(w3, bf2f(u3), acc);
        den += (w0 + w1) + (w2 + w3);
    }
    for (; i < end; ++i) {
        int s0 = RFL(ssrc[i]);
        float2 e0 = a2[2 * s0];
        float w0 = fmaxf(e0.x * eadp, e0.y * eadn);
        acc = fmaf(w0, bf2f(hb_in[(size_t)s0 * HD + lane]), acc);
        den += w0;
    }
    accN = acc; denN = den;
}

// aggregate layer l + fused transform of layer l+1 (LDS float4 dot)
__global__ __launch_bounds__(256) void k_aggr_ft(
    const int* __restrict__ row, const int* __restrict__ ssrc,
    const float4* __restrict__ a4_in,
    const unsigned short* __restrict__ hb_in,
    const float* __restrict__ bprev, const float* __restrict__ Wn,
    const float* __restrict__ asn, const float* __restrict__ adn,
    unsigned short* __restrict__ hb_out, float4* __restrict__ a4_out)
{
    __shared__ float sx[256];
    int wslot = RFL(threadIdx.x >> 6);
    int node = blockIdx.x * 4 + wslot;
    int lane = threadIdx.x & 63;

    float acc, den;
    aggr_core(node, lane, row, ssrc, a4_in, hb_in, acc, den);

    float xe = fmaf(acc, 1.f / den, bprev[lane]);
    xe = xe > 0.f ? xe : 0.f;
    sx[threadIdx.x] = xe;   // same-wave write/read: no barrier needed
    const float* sxw = sx + (threadIdx.x & 192);
    float hj = 0.f;
    #pragma unroll
    for (int k4 = 0; k4 < 16; ++k4) {
        float4 xv = reinterpret_cast<const float4*>(sxw)[k4];
        int kb = k4 * 4;
        hj = fmaf(xv.x, Wn[(kb + 0) * HD + lane], hj);
        hj = fmaf(xv.y, Wn[(kb + 1) * HD + lane], hj);
        hj = fmaf(xv.z, Wn[(kb + 2) * HD + lane], hj);
        hj = fmaf(xv.w, Wn[(kb + 3) * HD + lane], hj);
    }
    hb_out[(size_t)node * HD + lane] = f2bf(hj);
    float s = hj * asn[lane];
    float d = hj * adn[lane];
    #pragma unroll
    for (int off = 32; off > 0; off >>= 1) {
        s += __shfl_xor(s, off, 64);
        d += __shfl_xor(d, off, 64);
    }
    if (lane == 0) {
        float4 o;
        o.x = __expf(s); o.y = __expf(NEG_SLOPE * s);
        o.z = __expf(d); o.w = __expf(NEG_SLOPE * d);
        a4_out[node] = o;
    }
}

// aggregate last layer + fused gate
__global__ __launch_bounds__(256) void k_aggr_gate(
    const int* __restrict__ row, const int* __restrict__ ssrc,
    const float4* __restrict__ a4_in,
    const unsigned short* __restrict__ hb_in,
    const float* __restrict__ b2, const float* __restrict__ gate_w,
    const float* __restrict__ gate_b,
    float* __restrict__ h3out, float* __restrict__ gvals)
{
    int wslot = RFL(threadIdx.x >> 6);
    int node = blockIdx.x * 4 + wslot;
    int lane = threadIdx.x & 63;

    float acc, den;
    aggr_core(node, lane, row, ssrc, a4_in, hb_in, acc, den);

    float h3 = fmaf(acc, 1.f / den, b2[lane]);
    h3out[(size_t)node * HD + lane] = h3;
    float s = h3 * gate_w[lane];
    #pragma unroll
    for (int off = 32; off > 0; off >>= 1) s += __shfl_xor(s, off, 64);
    if (lane == 0) gvals[node] = s + gate_b[0];
}

__device__ __forceinline__ int lower_bound_batch(const int* __restrict__ batch, int val) {
    int lo = 0, hi = NN;
    while (lo < hi) { int mid = (lo + hi) >> 1; if (batch[mid] < val) lo = mid + 1; else hi = mid; }
    return lo;
}

// One block per graph: softmax-pool + fused final linear
__global__ __launch_bounds__(256) void k_pool(
    const float* __restrict__ h3, const float* __restrict__ gvals,
    const int* __restrict__ batch, const float* __restrict__ lin_w,
    const float* __restrict__ lin_b, float* __restrict__ out)
{
    __shared__ float red[256];
    __shared__ float pooled[HD];
    __shared__ float s_sumexp;
    int g = blockIdx.x;
    int tid = threadIdx.x;
    int start = lower_bound_batch(batch, g);
    int end   = lower_bound_batch(batch, g + 1);

    float local = 0.f;
    for (int n = start + tid; n < end; n += 256) local += __expf(gvals[n]);
    red[tid] = local;
    __syncthreads();
    #pragma unroll
    for (int s = 128; s > 0; s >>= 1) {
        if (tid < s) red[tid] += red[tid + s];
        __syncthreads();
    }
    if (tid == 0) s_sumexp = red[0];
    __syncthreads();
    float inv = 1.f / s_sumexp;

    int wid = tid >> 6, lane = tid & 63;
    float acc = 0.f;
    for (int n = start + wid; n < end; n += 4) {
        float c = __expf(gvals[n]) * inv;
        acc = fmaf(c, h3[(size_t)n * HD + lane], acc);
    }
    __syncthreads();
    red[tid] = acc;
    __syncthreads();
    if (tid < 64) pooled[tid] = red[tid] + red[tid + 64] + red[tid + 128] + red[tid + 192];
    __syncthreads();

    if (tid < 64) {
        float o = lin_b[tid];
        #pragma unroll 8
        for (int c = 0; c < HD; ++c) o = fmaf(pooled[c], lin_w[c * HD + tid], o);
        out[g * HD + tid] = o;
    }
}

extern "C" void kernel_launch(void* const* d_in, const int* in_sizes, int n_in,
                              void* d_out, int out_size, void* d_ws, size_t ws_size,
                              hipStream_t stream)
{
    const float* x     = (const float*)d_in[0];
    const int*  ei     = (const int*)d_in[1];
    const int*  batch  = (const int*)d_in[2];
    const float* W[3]  = {(const float*)d_in[3], (const float*)d_in[7],  (const float*)d_in[11]};
    const float* as[3] = {(const float*)d_in[4], (const float*)d_in[8],  (const float*)d_in[12]};
    const float* ad[3] = {(const float*)d_in[5], (const float*)d_in[9],  (const float*)d_in[13]};
    const float* bb[3] = {(const float*)d_in[6], (const float*)d_in[10], (const float*)d_in[14]};
    const float* gate_w = (const float*)d_in[15];
    const float* gate_b = (const float*)d_in[16];
    const float* lin_w  = (const float*)d_in[17];
    const float* lin_b  = (const float*)d_in[18];
    float* out = (float*)d_out;

    const int* esrc = ei;
    const int* edst = ei + NE;

    float* wsf = (float*)d_ws;
    size_t off = 0;
    float* h3buf = wsf + off; off += (size_t)NN * HD;
    float4* a4A  = (float4*)(wsf + off); off += (size_t)NN * 4;
    float4* a4B  = (float4*)(wsf + off); off += (size_t)NN * 4;
    float* gvals = wsf + off; off += NN;
    unsigned short* hbA = (unsigned short*)(wsf + off); off += (size_t)NN * HD / 2;
    unsigned short* hbB = (unsigned short*)(wsf + off); off += (size_t)NN * HD / 2;
    int* wsi = (int*)(wsf + off);
    size_t ioff = 0;
    int* deg    = wsi + ioff; ioff += NN;
    int* row    = wsi + ioff; ioff += NN + 1;
    int* cursor = wsi + ioff; ioff += NN;
    int* bsum   = wsi + ioff; ioff += NBLK;
    int* boff   = wsi + ioff; ioff += NBLK;
    int* ssrc   = wsi + ioff; ioff += NE;

    dim3 blk(256);
    const int nodeBlocks64 = NN / 4;     // wave per node
    const int edgeBlocks   = (NE + 255) / 256;

    // ---- CSR build (real edges only) ----
    (void)hipMemsetAsync(deg, 0, NN * sizeof(int), stream);
    k_hist<<<edgeBlocks, blk, 0, stream>>>(edst, deg);
    k_bsum<<<NBLK, blk, 0, stream>>>(deg, bsum);
    k_scanb<<<1, 512, 0, stream>>>(bsum, boff);
    k_scan2<<<NBLK, blk, 0, stream>>>(deg, boff, row, cursor);
    k_scatter<<<2048, blk, 0, stream>>>(esrc, edst, cursor, ssrc);

    // ---- layer 0 transform ----
    k_transform0<<<nodeBlocks64, blk, 0, stream>>>(x, W[0], as[0], ad[0],
                                                   hbA, a4A);
    // ---- layer 0 aggr + layer 1 transform ----
    k_aggr_ft<<<nodeBlocks64, blk, 0, stream>>>(row, ssrc, a4A, hbA,
                                                bb[0], W[1], as[1], ad[1],
                                                hbB, a4B);
    // ---- layer 1 aggr + layer 2 transform ----
    k_aggr_ft<<<nodeBlocks64, blk, 0, stream>>>(row, ssrc, a4B, hbB,
                                                bb[1], W[2], as[2], ad[2],
                                                hbA, a4A);
    // ---- layer 2 aggr + gate ----
    k_aggr_gate<<<nodeBlocks64, blk, 0, stream>>>(row, ssrc, a4A, hbA,
                                                  bb[2], gate_w, gate_b,
                                                  h3buf, gvals);
    // ---- pooling + final linear ----
    k_pool<<<NG, blk, 0, stream>>>(h3buf, gvals, batch, lin_w, lin_b, out);
}

// Round 15
// 384.946 us; speedup vs baseline: 1.5832x; 1.0351x over previous
//
#include <hip/hip_runtime.h>
#include <hip/hip_bf16.h>
#include <math.h>

#define NN 100000      // nodes
#define NE 1000000     // real edges (self-loops handled analytically)
#define HD 64          // hidden / feature dim
#define NG 128         // graphs
#define NEG_SLOPE 0.2f
#define NBLK 391       // ceil(NN/256)

__device__ __forceinline__ float bf2f(unsigned short u) {
    return __uint_as_float(((unsigned)u) << 16);
}
__device__ __forceinline__ unsigned short f2bf(float f) {
    __hip_bfloat16 h = __float2bfloat16(f);
    return *reinterpret_cast<unsigned short*>(&h);
}
__device__ __forceinline__ float lrelu_exp(float e) {
    e = e > 0.f ? e : NEG_SLOPE * e;
    return __expf(e);
}

// ---------------- CSR build (real edges only; deg memset to 0 outside) ----

__global__ __launch_bounds__(256) void k_hist(const int* __restrict__ edst,
                                              int* __restrict__ deg) {
    int e = blockIdx.x * 256 + threadIdx.x;
    if (e < NE) atomicAdd(&deg[edst[e]], 1);
}

__global__ __launch_bounds__(256) void k_bsum(const int* __restrict__ deg,
                                              int* __restrict__ bsum) {
    __shared__ int sm[256];
    int i = blockIdx.x * 256 + threadIdx.x;
    sm[threadIdx.x] = (i < NN) ? deg[i] : 0;
    __syncthreads();
    #pragma unroll
    for (int s = 128; s > 0; s >>= 1) {
        if (threadIdx.x < s) sm[threadIdx.x] += sm[threadIdx.x + s];
        __syncthreads();
    }
    if (threadIdx.x == 0) bsum[blockIdx.x] = sm[0];
}

__global__ __launch_bounds__(512) void k_scanb(const int* __restrict__ bsum,
                                               int* __restrict__ boff) {
    __shared__ int sm[512];
    int t = threadIdx.x;
    int v = (t < NBLK) ? bsum[t] : 0;
    sm[t] = v;
    __syncthreads();
    #pragma unroll
    for (int s = 1; s < 512; s <<= 1) {
        int add = (t >= s) ? sm[t - s] : 0;
        __syncthreads();
        sm[t] += add;
        __syncthreads();
    }
    if (t < NBLK) boff[t] = sm[t] - v;   // exclusive
}

__global__ __launch_bounds__(256) void k_scan2(const int* __restrict__ deg,
                                               const int* __restrict__ boff,
                                               int* __restrict__ row,
                                               int* __restrict__ cursor) {
    __shared__ int sm[256];
    int t = threadIdx.x, i = blockIdx.x * 256 + t;
    int v = (i < NN) ? deg[i] : 0;
    sm[t] = v;
    __syncthreads();
    #pragma unroll
    for (int s = 1; s < 256; s <<= 1) {
        int add = (t >= s) ? sm[t - s] : 0;
        __syncthreads();
        sm[t] += add;
        __syncthreads();
    }
    int excl = boff[blockIdx.x] + sm[t] - v;
    if (i < NN) { row[i] = excl; cursor[i] = excl; }
    if (i == NN - 1) row[NN] = excl + v;
}

// XCD-partitioned scatter: block (xcd = bid&7, chunk = bid>>3) processes
// edges [chunk*4096, ...+4096) but accepts only dst-groups ((d>>9)&7)==xcd.
// With bid%8 -> XCD round-robin, each 512-node group's ssrc/cursor lines
// stay resident in ONE XCD's L2 (writes coalesce there before eviction).
__global__ __launch_bounds__(256) void k_scatter(const int* __restrict__ esrc,
                                                 const int* __restrict__ edst,
                                                 int* __restrict__ cursor,
                                                 int* __restrict__ ssrc) {
    int xcd = blockIdx.x & 7;
    int chunk = blockIdx.x >> 3;
    int base = chunk * 4096;
    #pragma unroll 1
    for (int r = 0; r < 16; ++r) {
        int e = base + (r << 8) + threadIdx.x;
        if (e < NE) {
            int d = edst[e];
            if (((d >> 9) & 7) == xcd) {
                int pos = atomicAdd(&cursor[d], 1);
                ssrc[pos] = esrc[e];
            }
        }
    }
}

// ---------------- layer-0 transform (from fp32 x) ----------------
__global__ __launch_bounds__(256) void k_transform0(
    const float* __restrict__ inp, const float* __restrict__ W,
    const float* __restrict__ a_src, const float* __restrict__ a_dst,
    unsigned short* __restrict__ hb,
    float* __restrict__ alpha_s, float* __restrict__ alpha_d)
{
    __shared__ float sx[256];
    int node = (blockIdx.x * 256 + threadIdx.x) >> 6;
    int lane = threadIdx.x & 63;
    sx[threadIdx.x] = inp[(size_t)node * HD + lane];
    __syncthreads();
    const float* sxw = sx + (threadIdx.x & 192);
    float hj = 0.f;
    #pragma unroll
    for (int k4 = 0; k4 < 16; ++k4) {
        float4 xv = reinterpret_cast<const float4*>(sxw)[k4];
        int kb = k4 * 4;
        hj = fmaf(xv.x, W[(kb + 0) * HD + lane], hj);
        hj = fmaf(xv.y, W[(kb + 1) * HD + lane], hj);
        hj = fmaf(xv.z, W[(kb + 2) * HD + lane], hj);
        hj = fmaf(xv.w, W[(kb + 3) * HD + lane], hj);
    }
    hb[(size_t)node * HD + lane] = f2bf(hj);
    float s = hj * a_src[lane];
    float d = hj * a_dst[lane];
    #pragma unroll
    for (int off = 32; off > 0; off >>= 1) {
        s += __shfl_xor(s, off, 64);
        d += __shfl_xor(d, off, 64);
    }
    if (lane == 0) { alpha_s[node] = s; alpha_d[node] = d; }
}

// ------------- aggregate core: 1 node per wave, lane = channel ------------
// Wave-uniform edge walk (readfirstlane forces SGPR indices -> scalar loads
// for edge metadata, full-wave 128B gathers for h). 8-deep pipeline.
__device__ __forceinline__ void aggr_core(
    int node, int lane,
    const int* __restrict__ row, const int* __restrict__ ssrc,
    const float* __restrict__ as_in, const float* __restrict__ ad_in,
    const unsigned short* __restrict__ hb_in,
    float& accN, float& denN)
{
    int beg = row[node], end = row[node + 1];
    float ad = ad_in[node];
    // self loop
    float w = lrelu_exp(as_in[node] + ad);
    float acc = w * bf2f(hb_in[(size_t)node * HD + lane]);
    float den = w;
    int i = beg;
    for (; i + 8 <= end; i += 8) {
        int s0 = __builtin_amdgcn_readfirstlane(ssrc[i]);
        int s1 = __builtin_amdgcn_readfirstlane(ssrc[i + 1]);
        int s2 = __builtin_amdgcn_readfirstlane(ssrc[i + 2]);
        int s3 = __builtin_amdgcn_readfirstlane(ssrc[i + 3]);
        int s4 = __builtin_amdgcn_readfirstlane(ssrc[i + 4]);
        int s5 = __builtin_amdgcn_readfirstlane(ssrc[i + 5]);
        int s6 = __builtin_amdgcn_readfirstlane(ssrc[i + 6]);
        int s7 = __builtin_amdgcn_readfirstlane(ssrc[i + 7]);
        float a0 = as_in[s0], a1 = as_in[s1], a2 = as_in[s2], a3 = as_in[s3];
        float a4 = as_in[s4], a5 = as_in[s5], a6 = as_in[s6], a7 = as_in[s7];
        unsigned short u0 = hb_in[(size_t)s0 * HD + lane];
        unsigned short u1 = hb_in[(size_t)s1 * HD + lane];
        unsigned short u2 = hb_in[(size_t)s2 * HD + lane];
        unsigned short u3 = hb_in[(size_t)s3 * HD + lane];
        unsigned short u4 = hb_in[(size_t)s4 * HD + lane];
        unsigned short u5 = hb_in[(size_t)s5 * HD + lane];
        unsigned short u6 = hb_in[(size_t)s6 * HD + lane];
        unsigned short u7 = hb_in[(size_t)s7 * HD + lane];
        float w0 = lrelu_exp(a0 + ad), w1 = lrelu_exp(a1 + ad);
        float w2 = lrelu_exp(a2 + ad), w3 = lrelu_exp(a3 + ad);
        float w4 = lrelu_exp(a4 + ad), w5 = lrelu_exp(a5 + ad);
        float w6 = lrelu_exp(a6 + ad), w7 = lrelu_exp(a7 + ad);
        acc = fmaf(w0, bf2f(u0), acc);
        acc = fmaf(w1, bf2f(u1), acc);
        acc = fmaf(w2, bf2f(u2), acc);
        acc = fmaf(w3, bf2f(u3), acc);
        acc = fmaf(w4, bf2f(u4), acc);
        acc = fmaf(w5, bf2f(u5), acc);
        acc = fmaf(w6, bf2f(u6), acc);
        acc = fmaf(w7, bf2f(u7), acc);
        den += ((w0 + w1) + (w2 + w3)) + ((w4 + w5) + (w6 + w7));
    }
    for (; i + 4 <= end; i += 4) {
        int s0 = __builtin_amdgcn_readfirstlane(ssrc[i]);
        int s1 = __builtin_amdgcn_readfirstlane(ssrc[i + 1]);
        int s2 = __builtin_amdgcn_readfirstlane(ssrc[i + 2]);
        int s3 = __builtin_amdgcn_readfirstlane(ssrc[i + 3]);
        float a0 = as_in[s0], a1 = as_in[s1], a2 = as_in[s2], a3 = as_in[s3];
        unsigned short u0 = hb_in[(size_t)s0 * HD + lane];
        unsigned short u1 = hb_in[(size_t)s1 * HD + lane];
        unsigned short u2 = hb_in[(size_t)s2 * HD + lane];
        unsigned short u3 = hb_in[(size_t)s3 * HD + lane];
        float w0 = lrelu_exp(a0 + ad), w1 = lrelu_exp(a1 + ad);
        float w2 = lrelu_exp(a2 + ad), w3 = lrelu_exp(a3 + ad);
        acc = fmaf(w0, bf2f(u0), acc);
        acc = fmaf(w1, bf2f(u1), acc);
        acc = fmaf(w2, bf2f(u2), acc);
        acc = fmaf(w3, bf2f(u3), acc);
        den += (w0 + w1) + (w2 + w3);
    }
    for (; i < end; ++i) {
        int s0 = __builtin_amdgcn_readfirstlane(ssrc[i]);
        float w0 = lrelu_exp(as_in[s0] + ad);
        acc = fmaf(w0, bf2f(hb_in[(size_t)s0 * HD + lane]), acc);
        den += w0;
    }
    accN = acc; denN = den;
}

// aggregate layer l + fused transform of layer l+1 (LDS float4 dot)
__global__ __launch_bounds__(256) void k_aggr_ft(
    const int* __restrict__ row, const int* __restrict__ ssrc,
    const float* __restrict__ as_in, const float* __restrict__ ad_in,
    const unsigned short* __restrict__ hb_in,
    const float* __restrict__ bprev, const float* __restrict__ Wn,
    const float* __restrict__ asn, const float* __restrict__ adn,
    unsigned short* __restrict__ hb_out,
    float* __restrict__ as_out, float* __restrict__ ad_out)
{
    __shared__ float sx[256];
    int wslot = __builtin_amdgcn_readfirstlane(threadIdx.x >> 6);
    int node = blockIdx.x * 4 + wslot;
    int lane = threadIdx.x & 63;

    float acc, den;
    aggr_core(node, lane, row, ssrc, as_in, ad_in, hb_in, acc, den);

    float xe = fmaf(acc, 1.f / den, bprev[lane]);
    xe = xe > 0.f ? xe : 0.f;
    sx[threadIdx.x] = xe;   // same-wave write/read: no barrier needed
    const float* sxw = sx + (threadIdx.x & 192);
    float hj = 0.f;
    #pragma unroll
    for (int k4 = 0; k4 < 16; ++k4) {
        float4 xv = reinterpret_cast<const float4*>(sxw)[k4];
        int kb = k4 * 4;
        hj = fmaf(xv.x, Wn[(kb + 0) * HD + lane], hj);
        hj = fmaf(xv.y, Wn[(kb + 1) * HD + lane], hj);
        hj = fmaf(xv.z, Wn[(kb + 2) * HD + lane], hj);
        hj = fmaf(xv.w, Wn[(kb + 3) * HD + lane], hj);
    }
    hb_out[(size_t)node * HD + lane] = f2bf(hj);
    float s = hj * asn[lane];
    float d = hj * adn[lane];
    #pragma unroll
    for (int off = 32; off > 0; off >>= 1) {
        s += __shfl_xor(s, off, 64);
        d += __shfl_xor(d, off, 64);
    }
    if (lane == 0) { as_out[node] = s; ad_out[node] = d; }
}

// aggregate last layer + fused gate
__global__ __launch_bounds__(256) void k_aggr_gate(
    const int* __restrict__ row, const int* __restrict__ ssrc,
    const float* __restrict__ as_in, const float* __restrict__ ad_in,
    const unsigned short* __restrict__ hb_in,
    const float* __restrict__ b2, const float* __restrict__ gate_w,
    const float* __restrict__ gate_b,
    float* __restrict__ h3out, float* __restrict__ gvals)
{
    int wslot = __builtin_amdgcn_readfirstlane(threadIdx.x >> 6);
    int node = blockIdx.x * 4 + wslot;
    int lane = threadIdx.x & 63;

    float acc, den;
    aggr_core(node, lane, row, ssrc, as_in, ad_in, hb_in, acc, den);

    float h3 = fmaf(acc, 1.f / den, b2[lane]);
    h3out[(size_t)node * HD + lane] = h3;
    float s = h3 * gate_w[lane];
    #pragma unroll
    for (int off = 32; off > 0; off >>= 1) s += __shfl_xor(s, off, 64);
    if (lane == 0) gvals[node] = s + gate_b[0];
}

__device__ __forceinline__ int lower_bound_batch(const int* __restrict__ batch, int val) {
    int lo = 0, hi = NN;
    while (lo < hi) { int mid = (lo + hi) >> 1; if (batch[mid] < val) lo = mid + 1; else hi = mid; }
    return lo;
}

// One block per graph: softmax-pool + fused final linear
__global__ __launch_bounds__(256) void k_pool(
    const float* __restrict__ h3, const float* __restrict__ gvals,
    const int* __restrict__ batch, const float* __restrict__ lin_w,
    const float* __restrict__ lin_b, float* __restrict__ out)
{
    __shared__ float red[256];
    __shared__ float pooled[HD];
    __shared__ float s_sumexp;
    int g = blockIdx.x;
    int tid = threadIdx.x;
    int start = lower_bound_batch(batch, g);
    int end   = lower_bound_batch(batch, g + 1);

    float local = 0.f;
    for (int n = start + tid; n < end; n += 256) local += __expf(gvals[n]);
    red[tid] = local;
    __syncthreads();
    #pragma unroll
    for (int s = 128; s > 0; s >>= 1) {
        if (tid < s) red[tid] += red[tid + s];
        __syncthreads();
    }
    if (tid == 0) s_sumexp = red[0];
    __syncthreads();
    float inv = 1.f / s_sumexp;

    int wid = tid >> 6, lane = tid & 63;
    float acc = 0.f;
    for (int n = start + wid; n < end; n += 4) {
        float c = __expf(gvals[n]) * inv;
        acc = fmaf(c, h3[(size_t)n * HD + lane], acc);
    }
    __syncthreads();
    red[tid] = acc;
    __syncthreads();
    if (tid < 64) pooled[tid] = red[tid] + red[tid + 64] + red[tid + 128] + red[tid + 192];
    __syncthreads();

    if (tid < 64) {
        float o = lin_b[tid];
        #pragma unroll 8
        for (int c = 0; c < HD; ++c) o = fmaf(pooled[c], lin_w[c * HD + tid], o);
        out[g * HD + tid] = o;
    }
}

extern "C" void kernel_launch(void* const* d_in, const int* in_sizes, int n_in,
                              void* d_out, int out_size, void* d_ws, size_t ws_size,
                              hipStream_t stream)
{
    const float* x     = (const float*)d_in[0];
    const int*  ei     = (const int*)d_in[1];
    const int*  batch  = (const int*)d_in[2];
    const float* W[3]  = {(const float*)d_in[3], (const float*)d_in[7],  (const float*)d_in[11]};
    const float* as[3] = {(const float*)d_in[4], (const float*)d_in[8],  (const float*)d_in[12]};
    const float* ad[3] = {(const float*)d_in[5], (const float*)d_in[9],  (const float*)d_in[13]};
    const float* bb[3] = {(const float*)d_in[6], (const float*)d_in[10], (const float*)d_in[14]};
    const float* gate_w = (const float*)d_in[15];
    const float* gate_b = (const float*)d_in[16];
    const float* lin_w  = (const float*)d_in[17];
    const float* lin_b  = (const float*)d_in[18];
    float* out = (float*)d_out;

    const int* esrc = ei;
    const int* edst = ei + NE;

    float* wsf = (float*)d_ws;
    size_t off = 0;
    float* h3buf = wsf + off; off += (size_t)NN * HD;
    float* asA   = wsf + off; off += NN;
    float* adA   = wsf + off; off += NN;
    float* asB   = wsf + off; off += NN;
    float* adB   = wsf + off; off += NN;
    float* gvals = wsf + off; off += NN;
    unsigned short* hbA = (unsigned short*)(wsf + off); off += (size_t)NN * HD / 2;
    unsigned short* hbB = (unsigned short*)(wsf + off); off += (size_t)NN * HD / 2;
    int* wsi = (int*)(wsf + off);
    size_t ioff = 0;
    int* deg    = wsi + ioff; ioff += NN;
    int* row    = wsi + ioff; ioff += NN + 1;
    int* cursor = wsi + ioff; ioff += NN;
    int* bsum   = wsi + ioff; ioff += NBLK;
    int* boff   = wsi + ioff; ioff += NBLK;
    int* ssrc   = wsi + ioff; ioff += NE;

    dim3 blk(256);
    const int nodeBlocks64 = NN / 4;     // wave per node
    const int edgeBlocks   = (NE + 255) / 256;

    // ---- CSR build (real edges only) ----
    (void)hipMemsetAsync(deg, 0, NN * sizeof(int), stream);
    k_hist<<<edgeBlocks, blk, 0, stream>>>(edst, deg);
    k_bsum<<<NBLK, blk, 0, stream>>>(deg, bsum);
    k_scanb<<<1, 512, 0, stream>>>(bsum, boff);
    k_scan2<<<NBLK, blk, 0, stream>>>(deg, boff, row, cursor);
    k_scatter<<<2048, blk, 0, stream>>>(esrc, edst, cursor, ssrc);

    // ---- layer 0 transform ----
    k_transform0<<<nodeBlocks64, blk, 0, stream>>>(x, W[0], as[0], ad[0],
                                                   hbA, asA, adA);
    // ---- layer 0 aggr + layer 1 transform ----
    k_aggr_ft<<<nodeBlocks64, blk, 0, stream>>>(row, ssrc, asA, adA, hbA,
                                                bb[0], W[1], as[1], ad[1],
                                                hbB, asB, adB);
    // ---- layer 1 aggr + layer 2 transform ----
    k_aggr_ft<<<nodeBlocks64, blk, 0, stream>>>(row, ssrc, asB, adB, hbB,
                                                bb[1], W[2], as[2], ad[2],
                                                hbA, asA, adA);
    // ---- layer 2 aggr + gate ----
    k_aggr_gate<<<nodeBlocks64, blk, 0, stream>>>(row, ssrc, asA, adA, hbA,
                                                  bb[2], gate_w, gate_b,
                                                  h3buf, gvals);
    // ---- pooling + final linear ----
    k_pool<<<NG, blk, 0, stream>>>(h3buf, gvals, batch, lin_w, lin_b, out);
}